// Round 2
// baseline (3090.130 us; speedup 1.0000x reference)
//
#include <hip/hip_runtime.h>
#include <hip/hip_bf16.h>
#include <math.h>

#define B_ 2
#define N_ 2048
#define D_ 2048
#define H_ 16
#define HD_ 128
#define D3_ 6144

typedef __attribute__((ext_vector_type(8))) short bf16x8;
typedef __attribute__((ext_vector_type(4))) float f32x4;

__device__ __forceinline__ void gl_lds16(const void* g, void* l) {
  __builtin_amdgcn_global_load_lds(
      (const __attribute__((address_space(1))) void*)g,
      (__attribute__((address_space(3))) void*)l, 16, 0, 0);
}

__device__ __forceinline__ float bf2f(short s) {
  union { float f; unsigned u; } cv;
  cv.u = ((unsigned)(unsigned short)s) << 16;
  return cv.f;
}
__device__ __forceinline__ short f2bf(float f) {
  union { float f; unsigned u; } cv; cv.f = f;
  unsigned u = cv.u;
  unsigned r = (u + 0x7fffu + ((u >> 16) & 1u)) >> 16;  // round-to-nearest-even
  return (short)r;
}

// ---------------- elementwise fp32 -> bf16 ----------------
__global__ void k_cvt_x(const float* __restrict__ x, short* __restrict__ xb, int n) {
  int i = (blockIdx.x * 256 + threadIdx.x) * 4;
  if (i < n) {
    float4 v = *(const float4*)(x + i);
    short4 o;
    o.x = f2bf(v.x); o.y = f2bf(v.y); o.z = f2bf(v.z); o.w = f2bf(v.w);
    *(short4*)(xb + i) = o;
  }
}

// ---------------- tiled transpose + convert: in[R][C] fp32 -> out[C][R] bf16 ----------------
__global__ void k_transcvt(const float* __restrict__ in, short* __restrict__ out, int R, int C) {
  __shared__ float t[64][65];
  int r0 = blockIdx.y * 64, c0 = blockIdx.x * 64;
  for (int e = threadIdx.x; e < 64 * 64; e += 256) {
    int r = e >> 6, c = e & 63;
    t[r][c] = in[(long)(r0 + r) * C + c0 + c];
  }
  __syncthreads();
  for (int e = threadIdx.x; e < 64 * 64; e += 256) {
    int c = e >> 6, r = e & 63;
    out[(long)(c0 + c) * R + r0 + r] = f2bf(t[r][c]);
  }
}

// ---------------- bf16 MFMA GEMM: C[M,Nn] = A[M,K] * BT[Nn,K]^T + bias ----------------
// mode 0: write fp32 to outf[M,Nn]
// mode 1: write bf16 to outb[M,Nn]; cols >= D_ also go fp32 to kvout [2,B,H,N,HD]
__global__ __launch_bounds__(256) void k_gemm(
    const short* __restrict__ A, const short* __restrict__ BT,
    const float* __restrict__ bias, int M, int Nn, int K, int mode,
    short* __restrict__ outb, float* __restrict__ outf, float* __restrict__ kvout)
{
  __shared__ __align__(16) short As[128 * 32];
  __shared__ __align__(16) short Bs[128 * 32];
  int wave = threadIdx.x >> 6, lane = threadIdx.x & 63;
  int quad = lane >> 4, l15 = lane & 15;
  int m0 = blockIdx.y * 128, n0 = blockIdx.x * 128;
  int wm = wave >> 1, wn = wave & 1;
  f32x4 acc[4][4] = {};

  for (int k0 = 0; k0 < K; k0 += 32) {
    const short* gaa = A + (long)(m0 + wave * 32 + (lane >> 2)) * K + k0 + (lane & 3) * 8;
    gl_lds16(gaa,           As + (wave * 32) * 32);
    gl_lds16(gaa + 16 * K,  As + (wave * 32 + 16) * 32);
    const short* gbb = BT + (long)(n0 + wave * 32 + (lane >> 2)) * K + k0 + (lane & 3) * 8;
    gl_lds16(gbb,           Bs + (wave * 32) * 32);
    gl_lds16(gbb + 16 * K,  Bs + (wave * 32 + 16) * 32);
    __syncthreads();
    bf16x8 af[4], bfr[4];
    for (int mi = 0; mi < 4; mi++)
      af[mi] = *(const bf16x8*)(As + (wm * 64 + mi * 16 + l15) * 32 + quad * 8);
    for (int ni = 0; ni < 4; ni++)
      bfr[ni] = *(const bf16x8*)(Bs + (wn * 64 + ni * 16 + l15) * 32 + quad * 8);
    for (int mi = 0; mi < 4; mi++)
      for (int ni = 0; ni < 4; ni++)
        acc[mi][ni] = __builtin_amdgcn_mfma_f32_16x16x32_bf16(af[mi], bfr[ni], acc[mi][ni], 0, 0, 0);
    __syncthreads();
  }

  int row_base = m0 + wm * 64;
  int col_base = n0 + wn * 64;
  for (int mi = 0; mi < 4; mi++) {
    for (int ni = 0; ni < 4; ni++) {
      int col = col_base + ni * 16 + l15;
      float bv = bias[col];
      for (int reg = 0; reg < 4; reg++) {
        int row = row_base + mi * 16 + quad * 4 + reg;
        float v = acc[mi][ni][reg] + bv;
        if (mode == 0) {
          outf[(long)row * Nn + col] = v;
        } else {
          outb[(long)row * Nn + col] = f2bf(v);
          if (col >= D_) {
            int sel = (col >= 2 * D_) ? 1 : 0;
            int c2 = col - D_ - sel * D_;
            int h = c2 >> 7, d = c2 & 127;
            int b = row >> 11, n = row & 2047;
            kvout[((((long)sel * B_ + b) * H_ + h) * N_ + n) * HD_ + d] = v;
          }
        }
      }
    }
  }
}

// ---------------- RoPE on q,k (bf16 in, bf16 out); q also scaled by 1/sqrt(HD) ----------------
__global__ void k_rope(const short* __restrict__ qkvb, const float* __restrict__ fq,
                       const float* __restrict__ fk, short* __restrict__ qr,
                       short* __restrict__ kr)
{
  int t = blockIdx.x * 256 + threadIdx.x;  // ((b*H+h)*N + n)*64 + i
  int i = t & 63;
  int n = (t >> 6) & (N_ - 1);
  int bh = t >> 17;
  int b = bh >> 4, h = bh & 15;
  long qrow = ((long)b * N_ + n) * D3_;
  float q0 = bf2f(qkvb[qrow + h * 128 + 2 * i]);
  float q1 = bf2f(qkvb[qrow + h * 128 + 2 * i + 1]);
  float k0 = bf2f(qkvb[qrow + D_ + h * 128 + 2 * i]);
  float k1 = bf2f(qkvb[qrow + D_ + h * 128 + 2 * i + 1]);
  float aq = fq[n * 64 + i], ak = fk[n * 64 + i];
  float cq, sq, ck, sk;
  __sincosf(aq, &sq, &cq);
  __sincosf(ak, &sk, &ck);
  const float qs = 0.08838834764831845f;  // 1/sqrt(128), folds score scaling
  long orow = ((long)bh * N_ + n) * HD_;
  qr[orow + 2 * i]     = f2bf((q0 * cq - q1 * sq) * qs);
  qr[orow + 2 * i + 1] = f2bf((q0 * sq + q1 * cq) * qs);
  kr[orow + 2 * i]     = f2bf(k0 * ck - k1 * sk);
  kr[orow + 2 * i + 1] = f2bf(k0 * sk + k1 * ck);
}

// ---------------- V transpose: qkv v-region -> vt [B,H,HD,N] bf16 ----------------
__global__ void k_vtrans(const short* __restrict__ qkvb, short* __restrict__ vt) {
  __shared__ short t[64][130];
  int nt = blockIdx.x & 31;
  int h = (blockIdx.x >> 5) & 15;
  int b = blockIdx.x >> 9;
  int n0 = nt * 64;
  for (int e = threadIdx.x; e < 64 * 128; e += 256) {
    int r = e >> 7, d = e & 127;
    t[r][d] = qkvb[((long)b * N_ + n0 + r) * D3_ + 2 * D_ + h * 128 + d];
  }
  __syncthreads();
  for (int e = threadIdx.x; e < 64 * 128; e += 256) {
    int d = e >> 6, r = e & 63;
    vt[(((long)(b * H_ + h)) * HD_ + d) * N_ + n0 + r] = t[r][d];
  }
}

// ---------------- flash attention: qr,kr [B,H,N,HD], vt [B,H,HD,N] -> ao [B,N,H*HD] bf16 ----------------
__global__ __launch_bounds__(256) void k_flash(
    const short* __restrict__ qr, const short* __restrict__ kr,
    const short* __restrict__ vt, const int* __restrict__ amask,
    short* __restrict__ ao)
{
  __shared__ __align__(16) short Qs[64 * 128];
  __shared__ __align__(16) short Ks[64 * 128];
  __shared__ __align__(16) short Vs[128 * 64];
  __shared__ __align__(16) short Ps[4][16 * 64];
  int qt = blockIdx.x & 31, h = (blockIdx.x >> 5) & 15, b = blockIdx.x >> 9;
  int wave = threadIdx.x >> 6, lane = threadIdx.x & 63;
  int quad = lane >> 4, l15 = lane & 15;
  int q0 = qt * 64;
  long bh = (long)b * H_ + h;

  // stage Q tile (64 rows x 128) once
  for (int c = 0; c < 4; c++) {
    const short* g = qr + (bh * N_ + q0 + wave * 16 + c * 4 + (lane >> 4)) * HD_ + l15 * 8;
    gl_lds16(g, Qs + (wave * 16 + c * 4) * 128);
  }
  __syncthreads();
  bf16x8 aq[4];
  for (int kt = 0; kt < 4; kt++)
    aq[kt] = *(const bf16x8*)(Qs + (wave * 16 + l15) * 128 + kt * 32 + quad * 8);

  f32x4 o[8] = {};
  float mrow[4] = {-3e38f, -3e38f, -3e38f, -3e38f};
  float lrow[4] = {0.f, 0.f, 0.f, 0.f};
  int rowq[4];
  for (int reg = 0; reg < 4; reg++) rowq[reg] = q0 + wave * 16 + quad * 4 + reg;

  for (int kvt = 0; kvt <= qt; kvt++) {
    int kv0 = kvt * 64;
    __syncthreads();  // previous tile's LDS reads done before restaging
    for (int c = 0; c < 4; c++) {
      const short* g = kr + (bh * N_ + kv0 + wave * 16 + c * 4 + (lane >> 4)) * HD_ + l15 * 8;
      gl_lds16(g, Ks + (wave * 16 + c * 4) * 128);
    }
    for (int c = 0; c < 4; c++) {
      const short* g = vt + (bh * HD_ + wave * 32 + c * 8 + (lane >> 3)) * N_ + kv0 + (lane & 7) * 8;
      gl_lds16(g, Vs + (wave * 32 + c * 8) * 64);
    }
    __syncthreads();

    f32x4 s[4] = {};
    for (int kt = 0; kt < 4; kt++) {
      for (int nt = 0; nt < 4; nt++) {
        bf16x8 bk = *(const bf16x8*)(Ks + (nt * 16 + l15) * 128 + kt * 32 + quad * 8);
        s[nt] = __builtin_amdgcn_mfma_f32_16x16x32_bf16(aq[kt], bk, s[nt], 0, 0, 0);
      }
    }
    // causal + attention mask
    for (int nt = 0; nt < 4; nt++) {
      int col = kv0 + nt * 16 + l15;
      bool cm = (amask[b * N_ + col] == 0);
      for (int reg = 0; reg < 4; reg++) {
        if (cm || col > rowq[reg]) s[nt][reg] = -3e38f;
      }
    }
    // online softmax stats (rows live across the 16 lanes of each quad)
    float mn[4], alpha[4];
    for (int reg = 0; reg < 4; reg++) {
      float pm = fmaxf(fmaxf(s[0][reg], s[1][reg]), fmaxf(s[2][reg], s[3][reg]));
      for (int x = 1; x < 16; x <<= 1) pm = fmaxf(pm, __shfl_xor(pm, x, 64));
      mn[reg] = fmaxf(mrow[reg], pm);
      alpha[reg] = __expf(mrow[reg] - mn[reg]);
      mrow[reg] = mn[reg];
    }
    float rs[4] = {0.f, 0.f, 0.f, 0.f};
    for (int nt = 0; nt < 4; nt++)
      for (int reg = 0; reg < 4; reg++) {
        float p = __expf(s[nt][reg] - mn[reg]);
        s[nt][reg] = p;
        rs[reg] += p;
      }
    for (int reg = 0; reg < 4; reg++) {
      for (int x = 1; x < 16; x <<= 1) rs[reg] += __shfl_xor(rs[reg], x, 64);
      lrow[reg] = lrow[reg] * alpha[reg] + rs[reg];
    }
    // P (C-layout) -> LDS -> A-layout
    short* pw = Ps[wave];
    for (int nt = 0; nt < 4; nt++)
      for (int reg = 0; reg < 4; reg++)
        pw[(quad * 4 + reg) * 64 + nt * 16 + l15] = f2bf(s[nt][reg]);
    // rescale O
    for (int nt2 = 0; nt2 < 8; nt2++)
      for (int reg = 0; reg < 4; reg++)
        o[nt2][reg] *= alpha[reg];
    asm volatile("s_waitcnt lgkmcnt(0)" ::: "memory");
    // P @ V
    for (int kt2 = 0; kt2 < 2; kt2++) {
      bf16x8 ap = *(const bf16x8*)(pw + l15 * 64 + kt2 * 32 + quad * 8);
      for (int nt2 = 0; nt2 < 8; nt2++) {
        bf16x8 bv = *(const bf16x8*)(Vs + (nt2 * 16 + l15) * 64 + kt2 * 32 + quad * 8);
        o[nt2] = __builtin_amdgcn_mfma_f32_16x16x32_bf16(ap, bv, o[nt2], 0, 0, 0);
      }
    }
  }

  // epilogue: normalize and write attn output in [b, n, h*128+d] layout
  for (int reg = 0; reg < 4; reg++) lrow[reg] = 1.0f / lrow[reg];
  for (int nt2 = 0; nt2 < 8; nt2++)
    for (int reg = 0; reg < 4; reg++) {
      int n = q0 + wave * 16 + quad * 4 + reg;
      int d = h * 128 + nt2 * 16 + l15;
      ao[((long)b * N_ + n) * D_ + d] = f2bf(o[nt2][reg] * lrow[reg]);
    }
}

extern "C" void kernel_launch(void* const* d_in, const int* in_sizes, int n_in,
                              void* d_out, int out_size, void* d_ws, size_t ws_size,
                              hipStream_t stream) {
  const float* x    = (const float*)d_in[0];
  const float* fq   = (const float*)d_in[1];
  const float* fk   = (const float*)d_in[2];
  const int*   am   = (const int*)d_in[3];
  // d_in[4] = causal mask (tril) — causality computed analytically
  const float* Wqkv = (const float*)d_in[5];
  const float* bqkv = (const float*)d_in[6];
  const float* Wout = (const float*)d_in[7];
  const float* bout = (const float*)d_in[8];

  float* out = (float*)d_out;
  float* kvout = out + (long)B_ * N_ * D_;

  char* ws = (char*)d_ws;
  const size_t need = 167772160;  // 160 MB
  if (ws_size < need) return;
  short* xb    = (short*)(ws);
  short* wqkvT = (short*)(ws + 16777216);
  short* woutT = (short*)(ws + 41943040);
  short* qkvb  = (short*)(ws + 50331648);
  short* qrb   = (short*)(ws + 100663296);
  short* krb   = (short*)(ws + 117440512);
  short* vtb   = (short*)(ws + 134217728);
  short* aob   = (short*)(ws + 150994944);

  k_cvt_x<<<8192, 256, 0, stream>>>(x, xb, B_ * N_ * D_);
  k_transcvt<<<dim3(D3_ / 64, D_ / 64), 256, 0, stream>>>(Wqkv, wqkvT, D_, D3_);
  k_transcvt<<<dim3(D_ / 64, D_ / 64), 256, 0, stream>>>(Wout, woutT, D_, D_);
  k_gemm<<<dim3(D3_ / 128, (B_ * N_) / 128), 256, 0, stream>>>(
      xb, wqkvT, bqkv, B_ * N_, D3_, D_, 1, qkvb, nullptr, kvout);
  k_rope<<<16384, 256, 0, stream>>>(qkvb, fq, fk, qrb, krb);
  k_vtrans<<<1024, 256, 0, stream>>>(qkvb, vtb);
  k_flash<<<1024, 256, 0, stream>>>(qrb, krb, vtb, am, aob);
  k_gemm<<<dim3(D_ / 128, (B_ * N_) / 128), 256, 0, stream>>>(
      aob, woutT, bout, B_ * N_, D_, D_, 0, nullptr, out, nullptr);
}

// Round 3
// 688.506 us; speedup vs baseline: 4.4882x; 4.4882x over previous
//
#include <hip/hip_runtime.h>
#include <hip/hip_bf16.h>
#include <math.h>

#define B_ 2
#define N_ 2048
#define D_ 2048
#define H_ 16
#define HD_ 128
#define D3_ 6144

typedef __attribute__((ext_vector_type(8))) short bf16x8;
typedef __attribute__((ext_vector_type(4))) float f32x4;

__device__ __forceinline__ void gl_lds16(const void* g, void* l) {
  __builtin_amdgcn_global_load_lds(
      (const __attribute__((address_space(1))) void*)g,
      (__attribute__((address_space(3))) void*)l, 16, 0, 0);
}

__device__ __forceinline__ float bf2f(short s) {
  union { float f; unsigned u; } cv;
  cv.u = ((unsigned)(unsigned short)s) << 16;
  return cv.f;
}
__device__ __forceinline__ short f2bf(float f) {
  union { float f; unsigned u; } cv; cv.f = f;
  unsigned u = cv.u;
  unsigned r = (u + 0x7fffu + ((u >> 16) & 1u)) >> 16;  // round-to-nearest-even
  return (short)r;
}

// ---------------- elementwise fp32 -> bf16 ----------------
__global__ void k_cvt_x(const float* __restrict__ x, short* __restrict__ xb, int n) {
  int i = (blockIdx.x * 256 + threadIdx.x) * 4;
  if (i < n) {
    float4 v = *(const float4*)(x + i);
    short4 o;
    o.x = f2bf(v.x); o.y = f2bf(v.y); o.z = f2bf(v.z); o.w = f2bf(v.w);
    *(short4*)(xb + i) = o;
  }
}

// ---------------- tiled transpose + convert: in[R][C] fp32 -> out[C][R] bf16 ----------------
__global__ void k_transcvt(const float* __restrict__ in, short* __restrict__ out, int R, int C) {
  __shared__ float t[64][65];
  int r0 = blockIdx.y * 64, c0 = blockIdx.x * 64;
  #pragma unroll
  for (int e0 = 0; e0 < 16; e0++) {
    int e = e0 * 256 + threadIdx.x;
    int r = e >> 6, c = e & 63;
    t[r][c] = in[(long)(r0 + r) * C + c0 + c];
  }
  __syncthreads();
  #pragma unroll
  for (int e0 = 0; e0 < 16; e0++) {
    int e = e0 * 256 + threadIdx.x;
    int c = e >> 6, r = e & 63;
    out[(long)(c0 + c) * R + r0 + r] = f2bf(t[r][c]);
  }
}

// ---------------- bf16 MFMA GEMM: C[M,Nn] = A[M,K] * BT[Nn,K]^T + bias ----------------
// mode 0: write fp32 to outf[M,Nn]
// mode 1: write bf16 to outb[M,Nn]; cols >= D_ also go fp32 to kvout [2,B,H,N,HD]
__global__ __launch_bounds__(256) void k_gemm(
    const short* __restrict__ A, const short* __restrict__ BT,
    const float* __restrict__ bias, int M, int Nn, int K, int mode,
    short* __restrict__ outb, float* __restrict__ outf, float* __restrict__ kvout)
{
  __shared__ __align__(16) short As[128 * 32];
  __shared__ __align__(16) short Bs[128 * 32];
  int wave = threadIdx.x >> 6, lane = threadIdx.x & 63;
  int quad = lane >> 4, l15 = lane & 15;
  int m0 = blockIdx.y * 128, n0 = blockIdx.x * 128;
  int wm = wave >> 1, wn = wave & 1;
  f32x4 acc[4][4] = {};

  for (int k0 = 0; k0 < K; k0 += 32) {
    const short* gaa = A + (long)(m0 + wave * 32 + (lane >> 2)) * K + k0 + (lane & 3) * 8;
    gl_lds16(gaa,           As + (wave * 32) * 32);
    gl_lds16(gaa + 16 * K,  As + (wave * 32 + 16) * 32);
    const short* gbb = BT + (long)(n0 + wave * 32 + (lane >> 2)) * K + k0 + (lane & 3) * 8;
    gl_lds16(gbb,           Bs + (wave * 32) * 32);
    gl_lds16(gbb + 16 * K,  Bs + (wave * 32 + 16) * 32);
    __syncthreads();
    bf16x8 af[4], bfr[4];
    #pragma unroll
    for (int mi = 0; mi < 4; mi++)
      af[mi] = *(const bf16x8*)(As + (wm * 64 + mi * 16 + l15) * 32 + quad * 8);
    #pragma unroll
    for (int ni = 0; ni < 4; ni++)
      bfr[ni] = *(const bf16x8*)(Bs + (wn * 64 + ni * 16 + l15) * 32 + quad * 8);
    #pragma unroll
    for (int mi = 0; mi < 4; mi++)
      #pragma unroll
      for (int ni = 0; ni < 4; ni++)
        acc[mi][ni] = __builtin_amdgcn_mfma_f32_16x16x32_bf16(af[mi], bfr[ni], acc[mi][ni], 0, 0, 0);
    __syncthreads();
  }

  int row_base = m0 + wm * 64;
  int col_base = n0 + wn * 64;
  #pragma unroll
  for (int mi = 0; mi < 4; mi++) {
    #pragma unroll
    for (int ni = 0; ni < 4; ni++) {
      int col = col_base + ni * 16 + l15;
      float bv = bias[col];
      #pragma unroll
      for (int reg = 0; reg < 4; reg++) {
        int row = row_base + mi * 16 + quad * 4 + reg;
        float v = acc[mi][ni][reg] + bv;
        if (mode == 0) {
          outf[(long)row * Nn + col] = v;
        } else {
          outb[(long)row * Nn + col] = f2bf(v);
          if (col >= D_) {
            int sel = (col >= 2 * D_) ? 1 : 0;
            int c2 = col - D_ - sel * D_;
            int h = c2 >> 7, d = c2 & 127;
            int b = row >> 11, n = row & 2047;
            kvout[((((long)sel * B_ + b) * H_ + h) * N_ + n) * HD_ + d] = v;
          }
        }
      }
    }
  }
}

// ---------------- RoPE on q,k (bf16 in, bf16 out); q also scaled by 1/sqrt(HD) ----------------
__global__ void k_rope(const short* __restrict__ qkvb, const float* __restrict__ fq,
                       const float* __restrict__ fk, short* __restrict__ qr,
                       short* __restrict__ kr)
{
  int t = blockIdx.x * 256 + threadIdx.x;  // ((b*H+h)*N + n)*64 + i
  int i = t & 63;
  int n = (t >> 6) & (N_ - 1);
  int bh = t >> 17;
  int b = bh >> 4, h = bh & 15;
  long qrow = ((long)b * N_ + n) * D3_;
  float q0 = bf2f(qkvb[qrow + h * 128 + 2 * i]);
  float q1 = bf2f(qkvb[qrow + h * 128 + 2 * i + 1]);
  float k0 = bf2f(qkvb[qrow + D_ + h * 128 + 2 * i]);
  float k1 = bf2f(qkvb[qrow + D_ + h * 128 + 2 * i + 1]);
  float aq = fq[n * 64 + i], ak = fk[n * 64 + i];
  float cq, sq, ck, sk;
  __sincosf(aq, &sq, &cq);
  __sincosf(ak, &sk, &ck);
  const float qs = 0.08838834764831845f;  // 1/sqrt(128), folds score scaling
  long orow = ((long)bh * N_ + n) * HD_;
  qr[orow + 2 * i]     = f2bf((q0 * cq - q1 * sq) * qs);
  qr[orow + 2 * i + 1] = f2bf((q0 * sq + q1 * cq) * qs);
  kr[orow + 2 * i]     = f2bf(k0 * ck - k1 * sk);
  kr[orow + 2 * i + 1] = f2bf(k0 * sk + k1 * ck);
}

// ---------------- V transpose: qkv v-region -> vt [B,H,HD,N] bf16 ----------------
__global__ void k_vtrans(const short* __restrict__ qkvb, short* __restrict__ vt) {
  __shared__ short t[64][130];
  int nt = blockIdx.x & 31;
  int h = (blockIdx.x >> 5) & 15;
  int b = blockIdx.x >> 9;
  int n0 = nt * 64;
  #pragma unroll
  for (int e0 = 0; e0 < 32; e0++) {
    int e = e0 * 256 + threadIdx.x;
    int r = e >> 7, d = e & 127;
    t[r][d] = qkvb[((long)b * N_ + n0 + r) * D3_ + 2 * D_ + h * 128 + d];
  }
  __syncthreads();
  #pragma unroll
  for (int e0 = 0; e0 < 32; e0++) {
    int e = e0 * 256 + threadIdx.x;
    int d = e >> 6, r = e & 63;
    vt[(((long)(b * H_ + h)) * HD_ + d) * N_ + n0 + r] = t[r][d];
  }
}

// ---------------- flash attention: qr,kr [B,H,N,HD], vt [B,H,HD,N] -> ao [B,N,H*HD] bf16 ----------------
__global__ __launch_bounds__(256) void k_flash(
    const short* __restrict__ qr, const short* __restrict__ kr,
    const short* __restrict__ vt, const int* __restrict__ amask,
    short* __restrict__ ao)
{
  __shared__ __align__(16) short Qs[64 * 128];
  __shared__ __align__(16) short Ks[64 * 128];
  __shared__ __align__(16) short Vs[128 * 64];
  __shared__ __align__(16) short Ps[4][16 * 64];
  int qt = blockIdx.x & 31, h = (blockIdx.x >> 5) & 15, b = blockIdx.x >> 9;
  int wave = threadIdx.x >> 6, lane = threadIdx.x & 63;
  int quad = lane >> 4, l15 = lane & 15;
  int q0 = qt * 64;
  long bh = (long)b * H_ + h;

  // stage Q tile (64 rows x 128) once
  #pragma unroll
  for (int c = 0; c < 4; c++) {
    const short* g = qr + (bh * N_ + q0 + wave * 16 + c * 4 + (lane >> 4)) * HD_ + l15 * 8;
    gl_lds16(g, Qs + (wave * 16 + c * 4) * 128);
  }
  __syncthreads();
  bf16x8 aq[4];
  #pragma unroll
  for (int kt = 0; kt < 4; kt++)
    aq[kt] = *(const bf16x8*)(Qs + (wave * 16 + l15) * 128 + kt * 32 + quad * 8);

  f32x4 o[8] = {};
  float mrow[4] = {-3e38f, -3e38f, -3e38f, -3e38f};
  float lrow[4] = {0.f, 0.f, 0.f, 0.f};
  int rowq[4];
  #pragma unroll
  for (int reg = 0; reg < 4; reg++) rowq[reg] = q0 + wave * 16 + quad * 4 + reg;

  for (int kvt = 0; kvt <= qt; kvt++) {
    int kv0 = kvt * 64;
    __syncthreads();  // previous tile's LDS reads done before restaging
    #pragma unroll
    for (int c = 0; c < 4; c++) {
      const short* g = kr + (bh * N_ + kv0 + wave * 16 + c * 4 + (lane >> 4)) * HD_ + l15 * 8;
      gl_lds16(g, Ks + (wave * 16 + c * 4) * 128);
    }
    #pragma unroll
    for (int c = 0; c < 4; c++) {
      const short* g = vt + (bh * HD_ + wave * 32 + c * 8 + (lane >> 3)) * N_ + kv0 + (lane & 7) * 8;
      gl_lds16(g, Vs + (wave * 32 + c * 8) * 64);
    }
    __syncthreads();

    f32x4 s[4] = {};
    #pragma unroll
    for (int kt = 0; kt < 4; kt++) {
      #pragma unroll
      for (int nt = 0; nt < 4; nt++) {
        bf16x8 bk = *(const bf16x8*)(Ks + (nt * 16 + l15) * 128 + kt * 32 + quad * 8);
        s[nt] = __builtin_amdgcn_mfma_f32_16x16x32_bf16(aq[kt], bk, s[nt], 0, 0, 0);
      }
    }
    // causal + attention mask
    #pragma unroll
    for (int nt = 0; nt < 4; nt++) {
      int col = kv0 + nt * 16 + l15;
      bool cm = (amask[b * N_ + col] == 0);
      #pragma unroll
      for (int reg = 0; reg < 4; reg++) {
        if (cm || col > rowq[reg]) s[nt][reg] = -3e38f;
      }
    }
    // online softmax stats (rows live across the 16 lanes of each quad)
    float mn[4], alpha[4];
    #pragma unroll
    for (int reg = 0; reg < 4; reg++) {
      float pm = fmaxf(fmaxf(s[0][reg], s[1][reg]), fmaxf(s[2][reg], s[3][reg]));
      #pragma unroll
      for (int x = 1; x < 16; x <<= 1) pm = fmaxf(pm, __shfl_xor(pm, x, 64));
      mn[reg] = fmaxf(mrow[reg], pm);
      alpha[reg] = __expf(mrow[reg] - mn[reg]);
      mrow[reg] = mn[reg];
    }
    float rs[4] = {0.f, 0.f, 0.f, 0.f};
    #pragma unroll
    for (int nt = 0; nt < 4; nt++)
      #pragma unroll
      for (int reg = 0; reg < 4; reg++) {
        float p = __expf(s[nt][reg] - mn[reg]);
        s[nt][reg] = p;
        rs[reg] += p;
      }
    #pragma unroll
    for (int reg = 0; reg < 4; reg++) {
      #pragma unroll
      for (int x = 1; x < 16; x <<= 1) rs[reg] += __shfl_xor(rs[reg], x, 64);
      lrow[reg] = lrow[reg] * alpha[reg] + rs[reg];
    }
    // P (C-layout) -> LDS -> A-layout
    short* pw = Ps[wave];
    #pragma unroll
    for (int nt = 0; nt < 4; nt++)
      #pragma unroll
      for (int reg = 0; reg < 4; reg++)
        pw[(quad * 4 + reg) * 64 + nt * 16 + l15] = f2bf(s[nt][reg]);
    // rescale O
    #pragma unroll
    for (int nt2 = 0; nt2 < 8; nt2++)
      #pragma unroll
      for (int reg = 0; reg < 4; reg++)
        o[nt2][reg] *= alpha[reg];
    asm volatile("s_waitcnt lgkmcnt(0)" ::: "memory");
    // P @ V
    #pragma unroll
    for (int kt2 = 0; kt2 < 2; kt2++) {
      bf16x8 ap = *(const bf16x8*)(pw + l15 * 64 + kt2 * 32 + quad * 8);
      #pragma unroll
      for (int nt2 = 0; nt2 < 8; nt2++) {
        bf16x8 bv = *(const bf16x8*)(Vs + (nt2 * 16 + l15) * 64 + kt2 * 32 + quad * 8);
        o[nt2] = __builtin_amdgcn_mfma_f32_16x16x32_bf16(ap, bv, o[nt2], 0, 0, 0);
      }
    }
  }

  // epilogue: normalize and write attn output in [b, n, h*128+d] layout
  #pragma unroll
  for (int reg = 0; reg < 4; reg++) lrow[reg] = 1.0f / lrow[reg];
  #pragma unroll
  for (int nt2 = 0; nt2 < 8; nt2++)
    #pragma unroll
    for (int reg = 0; reg < 4; reg++) {
      int n = q0 + wave * 16 + quad * 4 + reg;
      int d = h * 128 + nt2 * 16 + l15;
      ao[((long)b * N_ + n) * D_ + d] = f2bf(o[nt2][reg] * lrow[reg]);
    }
}

extern "C" void kernel_launch(void* const* d_in, const int* in_sizes, int n_in,
                              void* d_out, int out_size, void* d_ws, size_t ws_size,
                              hipStream_t stream) {
  const float* x    = (const float*)d_in[0];
  const float* fq   = (const float*)d_in[1];
  const float* fk   = (const float*)d_in[2];
  const int*   am   = (const int*)d_in[3];
  // d_in[4] = causal mask (tril) — causality computed analytically
  const float* Wqkv = (const float*)d_in[5];
  const float* bqkv = (const float*)d_in[6];
  const float* Wout = (const float*)d_in[7];
  const float* bout = (const float*)d_in[8];

  float* out = (float*)d_out;
  float* kvout = out + (long)B_ * N_ * D_;

  char* ws = (char*)d_ws;
  const size_t need = 167772160;  // 160 MB
  if (ws_size < need) return;
  short* xb    = (short*)(ws);
  short* wqkvT = (short*)(ws + 16777216);
  short* woutT = (short*)(ws + 41943040);
  short* qkvb  = (short*)(ws + 50331648);
  short* qrb   = (short*)(ws + 100663296);
  short* krb   = (short*)(ws + 117440512);
  short* vtb   = (short*)(ws + 134217728);
  short* aob   = (short*)(ws + 150994944);

  k_cvt_x<<<8192, 256, 0, stream>>>(x, xb, B_ * N_ * D_);
  k_transcvt<<<dim3(D3_ / 64, D_ / 64), 256, 0, stream>>>(Wqkv, wqkvT, D_, D3_);
  k_transcvt<<<dim3(D_ / 64, D_ / 64), 256, 0, stream>>>(Wout, woutT, D_, D_);
  k_gemm<<<dim3(D3_ / 128, (B_ * N_) / 128), 256, 0, stream>>>(
      xb, wqkvT, bqkv, B_ * N_, D3_, D_, 1, qkvb, nullptr, kvout);
  k_rope<<<16384, 256, 0, stream>>>(qkvb, fq, fk, qrb, krb);
  k_vtrans<<<1024, 256, 0, stream>>>(qkvb, vtb);
  k_flash<<<1024, 256, 0, stream>>>(qrb, krb, vtb, am, aob);
  k_gemm<<<dim3(D_ / 128, (B_ * N_) / 128), 256, 0, stream>>>(
      aob, woutT, bout, B_ * N_, D_, D_, 0, nullptr, out, nullptr);
}

// Round 4
// 557.154 us; speedup vs baseline: 5.5463x; 1.2358x over previous
//
#include <hip/hip_runtime.h>
#include <hip/hip_bf16.h>
#include <math.h>

#define B_ 2
#define N_ 2048
#define D_ 2048
#define H_ 16
#define HD_ 128
#define D3_ 6144

typedef __attribute__((ext_vector_type(8))) short bf16x8;
typedef __attribute__((ext_vector_type(4))) float f32x4;

__device__ __forceinline__ void gl_lds16(const void* g, void* l) {
  __builtin_amdgcn_global_load_lds(
      (const __attribute__((address_space(1))) void*)g,
      (__attribute__((address_space(3))) void*)l, 16, 0, 0);
}

__device__ __forceinline__ float bf2f(short s) {
  union { float f; unsigned u; } cv;
  cv.u = ((unsigned)(unsigned short)s) << 16;
  return cv.f;
}
__device__ __forceinline__ short f2bf(float f) {
  union { float f; unsigned u; } cv; cv.f = f;
  unsigned u = cv.u;
  unsigned r = (u + 0x7fffu + ((u >> 16) & 1u)) >> 16;  // round-to-nearest-even
  return (short)r;
}

// ---------------- elementwise fp32 -> bf16 ----------------
__global__ void k_cvt_x(const float* __restrict__ x, short* __restrict__ xb, int n) {
  int i = (blockIdx.x * 256 + threadIdx.x) * 4;
  if (i < n) {
    float4 v = *(const float4*)(x + i);
    short4 o;
    o.x = f2bf(v.x); o.y = f2bf(v.y); o.z = f2bf(v.z); o.w = f2bf(v.w);
    *(short4*)(xb + i) = o;
  }
}

// ---------------- tiled transpose + convert: in[R][C] fp32 -> out[C][R] bf16 ----------------
__global__ void k_transcvt(const float* __restrict__ in, short* __restrict__ out, int R, int C) {
  __shared__ float t[64][65];
  int r0 = blockIdx.y * 64, c0 = blockIdx.x * 64;
  #pragma unroll
  for (int e0 = 0; e0 < 16; e0++) {
    int e = e0 * 256 + threadIdx.x;
    int r = e >> 6, c = e & 63;
    t[r][c] = in[(long)(r0 + r) * C + c0 + c];
  }
  __syncthreads();
  #pragma unroll
  for (int e0 = 0; e0 < 16; e0++) {
    int e = e0 * 256 + threadIdx.x;
    int c = e >> 6, r = e & 63;
    out[(long)(c0 + c) * R + r0 + r] = f2bf(t[r][c]);
  }
}

// ---------------- bf16 MFMA GEMM: C[M,Nn] = A[M,K] * BT[Nn,K]^T + bias ----------------
__global__ __launch_bounds__(256) void k_gemm(
    const short* __restrict__ A, const short* __restrict__ BT,
    const float* __restrict__ bias, int M, int Nn, int K, int mode,
    short* __restrict__ outb, float* __restrict__ outf, float* __restrict__ kvout)
{
  __shared__ __align__(16) short As[128 * 32];
  __shared__ __align__(16) short Bs[128 * 32];
  int wave = threadIdx.x >> 6, lane = threadIdx.x & 63;
  int quad = lane >> 4, l15 = lane & 15;
  int m0 = blockIdx.y * 128, n0 = blockIdx.x * 128;
  int wm = wave >> 1, wn = wave & 1;
  f32x4 acc[4][4] = {};

  for (int k0 = 0; k0 < K; k0 += 32) {
    const short* gaa = A + (long)(m0 + wave * 32 + (lane >> 2)) * K + k0 + (lane & 3) * 8;
    gl_lds16(gaa,           As + (wave * 32) * 32);
    gl_lds16(gaa + 16 * K,  As + (wave * 32 + 16) * 32);
    const short* gbb = BT + (long)(n0 + wave * 32 + (lane >> 2)) * K + k0 + (lane & 3) * 8;
    gl_lds16(gbb,           Bs + (wave * 32) * 32);
    gl_lds16(gbb + 16 * K,  Bs + (wave * 32 + 16) * 32);
    __syncthreads();
    bf16x8 af[4], bfr[4];
    #pragma unroll
    for (int mi = 0; mi < 4; mi++)
      af[mi] = *(const bf16x8*)(As + (wm * 64 + mi * 16 + l15) * 32 + quad * 8);
    #pragma unroll
    for (int ni = 0; ni < 4; ni++)
      bfr[ni] = *(const bf16x8*)(Bs + (wn * 64 + ni * 16 + l15) * 32 + quad * 8);
    #pragma unroll
    for (int mi = 0; mi < 4; mi++)
      #pragma unroll
      for (int ni = 0; ni < 4; ni++)
        acc[mi][ni] = __builtin_amdgcn_mfma_f32_16x16x32_bf16(af[mi], bfr[ni], acc[mi][ni], 0, 0, 0);
    __syncthreads();
  }

  int row_base = m0 + wm * 64;
  int col_base = n0 + wn * 64;
  #pragma unroll
  for (int mi = 0; mi < 4; mi++) {
    #pragma unroll
    for (int ni = 0; ni < 4; ni++) {
      int col = col_base + ni * 16 + l15;
      float bv = bias[col];
      #pragma unroll
      for (int reg = 0; reg < 4; reg++) {
        int row = row_base + mi * 16 + quad * 4 + reg;
        float v = acc[mi][ni][reg] + bv;
        if (mode == 0) {
          outf[(long)row * Nn + col] = v;
        } else {
          outb[(long)row * Nn + col] = f2bf(v);
          if (col >= D_) {
            int sel = (col >= 2 * D_) ? 1 : 0;
            int c2 = col - D_ - sel * D_;
            int h = c2 >> 7, d = c2 & 127;
            int b = row >> 11, n = row & 2047;
            kvout[((((long)sel * B_ + b) * H_ + h) * N_ + n) * HD_ + d] = v;
          }
        }
      }
    }
  }
}

// ---------------- RoPE on q,k (bf16 in, bf16 out); q also scaled by 1/sqrt(HD) ----------------
__global__ void k_rope(const short* __restrict__ qkvb, const float* __restrict__ fq,
                       const float* __restrict__ fk, short* __restrict__ qr,
                       short* __restrict__ kr)
{
  int t = blockIdx.x * 256 + threadIdx.x;  // ((b*H+h)*N + n)*64 + i
  int i = t & 63;
  int n = (t >> 6) & (N_ - 1);
  int bh = t >> 17;
  int b = bh >> 4, h = bh & 15;
  long qrow = ((long)b * N_ + n) * D3_;
  float q0 = bf2f(qkvb[qrow + h * 128 + 2 * i]);
  float q1 = bf2f(qkvb[qrow + h * 128 + 2 * i + 1]);
  float k0 = bf2f(qkvb[qrow + D_ + h * 128 + 2 * i]);
  float k1 = bf2f(qkvb[qrow + D_ + h * 128 + 2 * i + 1]);
  float aq = fq[n * 64 + i], ak = fk[n * 64 + i];
  float cq, sq, ck, sk;
  __sincosf(aq, &sq, &cq);
  __sincosf(ak, &sk, &ck);
  const float qs = 0.08838834764831845f;  // 1/sqrt(128), folds score scaling
  long orow = ((long)bh * N_ + n) * HD_;
  qr[orow + 2 * i]     = f2bf((q0 * cq - q1 * sq) * qs);
  qr[orow + 2 * i + 1] = f2bf((q0 * sq + q1 * cq) * qs);
  kr[orow + 2 * i]     = f2bf(k0 * ck - k1 * sk);
  kr[orow + 2 * i + 1] = f2bf(k0 * sk + k1 * ck);
}

// ---------------- V transpose: qkv v-region -> vt [B,H,HD,N] bf16 ----------------
__global__ void k_vtrans(const short* __restrict__ qkvb, short* __restrict__ vt) {
  __shared__ short t[64][130];
  int nt = blockIdx.x & 31;
  int h = (blockIdx.x >> 5) & 15;
  int b = blockIdx.x >> 9;
  int n0 = nt * 64;
  #pragma unroll
  for (int e0 = 0; e0 < 32; e0++) {
    int e = e0 * 256 + threadIdx.x;
    int r = e >> 7, d = e & 127;
    t[r][d] = qkvb[((long)b * N_ + n0 + r) * D3_ + 2 * D_ + h * 128 + d];
  }
  __syncthreads();
  #pragma unroll
  for (int e0 = 0; e0 < 32; e0++) {
    int e = e0 * 256 + threadIdx.x;
    int d = e >> 6, r = e & 63;
    vt[(((long)(b * H_ + h)) * HD_ + d) * N_ + n0 + r] = t[r][d];
  }
}

// ---------------- flash attention, paired q-tiles + swizzled LDS ----------------
// qr,kr [B,H,N,HD], vt [B,H,HD,N] -> ao [B,N,H*HD] bf16
// block = (pair p, bh): q-tiles qa=p, qb=31-p. 512 blocks.
// LDS rows stored with XOR chunk swizzle: chunk slot c holds global chunk c ^ (row & 7).
__global__ __launch_bounds__(256) void k_flash(
    const short* __restrict__ qr, const short* __restrict__ kr,
    const short* __restrict__ vt, const int* __restrict__ amask,
    short* __restrict__ ao)
{
  __shared__ __align__(16) short QsA[64 * 128];
  __shared__ __align__(16) short QsB[64 * 128];
  __shared__ __align__(16) short Ks[64 * 128];
  __shared__ __align__(16) short Vs[128 * 64];
  __shared__ __align__(16) short Ps[4][16 * 72];  // padded stride 72 shorts (144 B)
  int p = blockIdx.x & 15, bhidx = blockIdx.x >> 4;
  int b = bhidx >> 4, h = bhidx & 15;
  int qa = p, qb = 31 - p;
  int wave = threadIdx.x >> 6, lane = threadIdx.x & 63;
  int quad = lane >> 4, l15 = lane & 15;
  long bh = (long)b * H_ + h;
  int q0A = qa * 64, q0B = qb * 64;

  // stage both Q tiles (swizzled)
  #pragma unroll
  for (int c = 0; c < 4; c++) {
    int rl = wave * 16 + c * 4 + (lane >> 4);
    int gc = (lane & 15) ^ (rl & 7);
    gl_lds16(qr + (bh * N_ + q0A + rl) * HD_ + gc * 8, QsA + (wave * 16 + c * 4) * 128);
    gl_lds16(qr + (bh * N_ + q0B + rl) * HD_ + gc * 8, QsB + (wave * 16 + c * 4) * 128);
  }
  __syncthreads();
  bf16x8 aqA[4], aqB[4];
  #pragma unroll
  for (int kt = 0; kt < 4; kt++) {
    int slot = (kt * 4 + quad) ^ (l15 & 7);
    aqA[kt] = *(const bf16x8*)(QsA + (wave * 16 + l15) * 128 + slot * 8);
    aqB[kt] = *(const bf16x8*)(QsB + (wave * 16 + l15) * 128 + slot * 8);
  }

  f32x4 oA[8] = {}, oB[8] = {};
  float mA[4] = {-3e38f, -3e38f, -3e38f, -3e38f}, mB[4] = {-3e38f, -3e38f, -3e38f, -3e38f};
  float lA[4] = {0.f, 0.f, 0.f, 0.f}, lB[4] = {0.f, 0.f, 0.f, 0.f};
  int rowA[4], rowB[4];
  #pragma unroll
  for (int reg = 0; reg < 4; reg++) {
    rowA[reg] = q0A + wave * 16 + quad * 4 + reg;
    rowB[reg] = q0B + wave * 16 + quad * 4 + reg;
  }
  short* pw = Ps[wave];

#define QSTEP(AQ, O, MR, LR, ROWQ)                                                     \
  {                                                                                    \
    f32x4 s[4] = {};                                                                   \
    _Pragma("unroll")                                                                  \
    for (int kt = 0; kt < 4; kt++) {                                                   \
      _Pragma("unroll")                                                                \
      for (int nt = 0; nt < 4; nt++) {                                                 \
        int slot = (kt * 4 + quad) ^ (l15 & 7);                                        \
        bf16x8 bk = *(const bf16x8*)(Ks + (nt * 16 + l15) * 128 + slot * 8);           \
        s[nt] = __builtin_amdgcn_mfma_f32_16x16x32_bf16(AQ[kt], bk, s[nt], 0, 0, 0);   \
      }                                                                                \
    }                                                                                  \
    _Pragma("unroll")                                                                  \
    for (int nt = 0; nt < 4; nt++) {                                                   \
      int col = kv0 + nt * 16 + l15;                                                   \
      bool cm = (amask[b * N_ + col] == 0);                                            \
      _Pragma("unroll")                                                                \
      for (int reg = 0; reg < 4; reg++)                                                \
        if (cm || col > ROWQ[reg]) s[nt][reg] = -3e38f;                                \
    }                                                                                  \
    float mn[4], alpha[4];                                                             \
    _Pragma("unroll")                                                                  \
    for (int reg = 0; reg < 4; reg++) {                                                \
      float pm = fmaxf(fmaxf(s[0][reg], s[1][reg]), fmaxf(s[2][reg], s[3][reg]));      \
      _Pragma("unroll")                                                                \
      for (int x = 1; x < 16; x <<= 1) pm = fmaxf(pm, __shfl_xor(pm, x, 64));          \
      mn[reg] = fmaxf(MR[reg], pm);                                                    \
      alpha[reg] = __expf(MR[reg] - mn[reg]);                                          \
      MR[reg] = mn[reg];                                                               \
    }                                                                                  \
    float rs[4] = {0.f, 0.f, 0.f, 0.f};                                                \
    _Pragma("unroll")                                                                  \
    for (int nt = 0; nt < 4; nt++)                                                     \
      _Pragma("unroll")                                                                \
      for (int reg = 0; reg < 4; reg++) {                                              \
        float pp = __expf(s[nt][reg] - mn[reg]);                                       \
        s[nt][reg] = pp;                                                               \
        rs[reg] += pp;                                                                 \
      }                                                                                \
    _Pragma("unroll")                                                                  \
    for (int reg = 0; reg < 4; reg++) {                                                \
      _Pragma("unroll")                                                                \
      for (int x = 1; x < 16; x <<= 1) rs[reg] += __shfl_xor(rs[reg], x, 64);          \
      LR[reg] = LR[reg] * alpha[reg] + rs[reg];                                        \
    }                                                                                  \
    _Pragma("unroll")                                                                  \
    for (int nt = 0; nt < 4; nt++)                                                     \
      _Pragma("unroll")                                                                \
      for (int reg = 0; reg < 4; reg++)                                                \
        pw[(quad * 4 + reg) * 72 + nt * 16 + l15] = f2bf(s[nt][reg]);                  \
    _Pragma("unroll")                                                                  \
    for (int nt2 = 0; nt2 < 8; nt2++)                                                  \
      _Pragma("unroll")                                                                \
      for (int reg = 0; reg < 4; reg++)                                                \
        O[nt2][reg] *= alpha[reg];                                                     \
    asm volatile("s_waitcnt lgkmcnt(0)" ::: "memory");                                 \
    _Pragma("unroll")                                                                  \
    for (int kt2 = 0; kt2 < 2; kt2++) {                                                \
      bf16x8 ap = *(const bf16x8*)(pw + l15 * 72 + kt2 * 32 + quad * 8);               \
      _Pragma("unroll")                                                                \
      for (int nt2 = 0; nt2 < 8; nt2++) {                                              \
        int slot2 = (kt2 * 4 + quad) ^ (l15 & 7);                                      \
        bf16x8 bv = *(const bf16x8*)(Vs + (nt2 * 16 + l15) * 64 + slot2 * 8);          \
        O[nt2] = __builtin_amdgcn_mfma_f32_16x16x32_bf16(ap, bv, O[nt2], 0, 0, 0);     \
      }                                                                                \
    }                                                                                  \
  }

  for (int kvt = 0; kvt <= qb; kvt++) {
    int kv0 = kvt * 64;
    __syncthreads();
    #pragma unroll
    for (int c = 0; c < 4; c++) {
      int rl = wave * 16 + c * 4 + (lane >> 4);
      int gc = (lane & 15) ^ (rl & 7);
      gl_lds16(kr + (bh * N_ + kv0 + rl) * HD_ + gc * 8, Ks + (wave * 16 + c * 4) * 128);
    }
    #pragma unroll
    for (int c = 0; c < 4; c++) {
      int rl = wave * 32 + c * 8 + (lane >> 3);
      int gc = (lane & 7) ^ (rl & 7);
      gl_lds16(vt + (bh * HD_ + rl) * N_ + kv0 + gc * 8, Vs + (wave * 32 + c * 8) * 64);
    }
    __syncthreads();

    QSTEP(aqB, oB, mB, lB, rowB);
    if (kvt <= qa) {
      QSTEP(aqA, oA, mA, lA, rowA);
    }
  }
#undef QSTEP

  // epilogue: normalize and write attn output in [b, n, h*128+d] layout
  #pragma unroll
  for (int reg = 0; reg < 4; reg++) { lA[reg] = 1.0f / lA[reg]; lB[reg] = 1.0f / lB[reg]; }
  #pragma unroll
  for (int nt2 = 0; nt2 < 8; nt2++)
    #pragma unroll
    for (int reg = 0; reg < 4; reg++) {
      int d = h * 128 + nt2 * 16 + l15;
      int nA = q0A + wave * 16 + quad * 4 + reg;
      int nB = q0B + wave * 16 + quad * 4 + reg;
      ao[((long)b * N_ + nA) * D_ + d] = f2bf(oA[nt2][reg] * lA[reg]);
      ao[((long)b * N_ + nB) * D_ + d] = f2bf(oB[nt2][reg] * lB[reg]);
    }
}

extern "C" void kernel_launch(void* const* d_in, const int* in_sizes, int n_in,
                              void* d_out, int out_size, void* d_ws, size_t ws_size,
                              hipStream_t stream) {
  const float* x    = (const float*)d_in[0];
  const float* fq   = (const float*)d_in[1];
  const float* fk   = (const float*)d_in[2];
  const int*   am   = (const int*)d_in[3];
  // d_in[4] = causal mask (tril) — causality computed analytically
  const float* Wqkv = (const float*)d_in[5];
  const float* bqkv = (const float*)d_in[6];
  const float* Wout = (const float*)d_in[7];
  const float* bout = (const float*)d_in[8];

  float* out = (float*)d_out;
  float* kvout = out + (long)B_ * N_ * D_;

  char* ws = (char*)d_ws;
  const size_t need = 167772160;  // 160 MB
  if (ws_size < need) return;
  short* xb    = (short*)(ws);
  short* wqkvT = (short*)(ws + 16777216);
  short* woutT = (short*)(ws + 41943040);
  short* qkvb  = (short*)(ws + 50331648);
  short* qrb   = (short*)(ws + 100663296);
  short* krb   = (short*)(ws + 117440512);
  short* vtb   = (short*)(ws + 134217728);
  short* aob   = (short*)(ws + 150994944);

  k_cvt_x<<<8192, 256, 0, stream>>>(x, xb, B_ * N_ * D_);
  k_transcvt<<<dim3(D3_ / 64, D_ / 64), 256, 0, stream>>>(Wqkv, wqkvT, D_, D3_);
  k_transcvt<<<dim3(D_ / 64, D_ / 64), 256, 0, stream>>>(Wout, woutT, D_, D_);
  k_gemm<<<dim3(D3_ / 128, (B_ * N_) / 128), 256, 0, stream>>>(
      xb, wqkvT, bqkv, B_ * N_, D3_, D_, 1, qkvb, nullptr, kvout);
  k_rope<<<16384, 256, 0, stream>>>(qkvb, fq, fk, qrb, krb);
  k_vtrans<<<1024, 256, 0, stream>>>(qkvb, vtb);
  k_flash<<<512, 256, 0, stream>>>(qrb, krb, vtb, am, aob);
  k_gemm<<<dim3(D_ / 128, (B_ * N_) / 128), 256, 0, stream>>>(
      aob, woutT, bout, B_ * N_, D_, D_, 0, nullptr, out, nullptr);
}